// Round 15
// baseline (78.837 us; speedup 1.0000x reference)
//
#include <hip/hip_runtime.h>
#include <math.h>

#define HH 96
#define WW 320
#define NP 8

typedef _Float16 half8_t  __attribute__((ext_vector_type(8)));
typedef _Float16 half4_t  __attribute__((ext_vector_type(4)));
typedef float    floatx16 __attribute__((ext_vector_type(16)));

struct ShiftInfo {
    int   s0[NP];
    float wa[NP];
    float wb[NP];
    int   rows[16];
};

// async global->LDS, 16B per lane, dest = wave-uniform base + lane*16
__device__ __forceinline__ void gl_lds16(const _Float16* g, _Float16* l) {
    __builtin_amdgcn_global_load_lds(
        (const __attribute__((address_space(1))) void*)g,
        (__attribute__((address_space(3))) void*)l, 16, 0, 0);
}

// blend LDS tile: element (row, chunk c) lives at row*64 + (c ^ (row&7))*8.
// Staged via linear global_load_lds with pre-swizzled SOURCE chunk.
#define CSW(row, c) (((row) * 64) + ((((c) ^ ((row) & 7))) * 8))

// ---------------------------------------------------------------------------
// prep: blockIdx.x < 768 -> transpose+cvt one (b,y,x-half) strip of X into Xt
//       blockIdx.x >= 768 -> weight cvt to MFMA-fragment-native layout.
// ---------------------------------------------------------------------------
__global__ __launch_bounds__(256) void prep_kernel(
    const float* __restrict__ X, const float* __restrict__ W1,
    const float* __restrict__ W2, _Float16* __restrict__ Xt,
    _Float16* __restrict__ Wf)
{
    __shared__ __align__(16) _Float16 Ls[64 * 163];
    const int bx = blockIdx.x, t = threadIdx.x;
    if (bx < 768) {
        const int r = bx >> 1, xh = bx & 1;
        const int y = r % HH, b = r / HH;
        const int xbase = xh * 160;
        for (int u = t; u < 64 * 40; u += 256) {
            int ci = u / 40;
            int xi = (u - ci * 40) * 4;
            float4 v = *(const float4*)&X[((size_t)(b * 64 + ci) * HH + y) * WW + xbase + xi];
            half4_t hv = { (_Float16)v.x, (_Float16)v.y, (_Float16)v.z, (_Float16)v.w };
            *(half4_t*)&Ls[ci * 163 + xi] = hv;
        }
        __syncthreads();
        const int ci8 = t & 7, xg = t >> 3;
        for (int it = 0; it < 5; ++it) {
            int x = xg + 32 * it;
            half8_t o;
#pragma unroll
            for (int j = 0; j < 8; ++j) o[j] = Ls[(ci8 * 8 + j) * 163 + x];
            *(half8_t*)&Xt[((size_t)(b * HH + y) * WW + xbase + x) * 64 + ci8 * 8] = o;
        }
    } else {
        const int k = bx - 768;                  // 0..17
        const int layer = k / 9, pos = k - layer * 9;
        const float* Ws = layer ? W2 : W1;
        _Float16* Wd = Wf + layer * 36864 + pos * 4096;
        for (int u = t; u < 4096; u += 256) {
            int mt  = u >> 11;
            int ks  = (u >> 9) & 3;
            int i31 = (u >> 4) & 31;
            int h   = (u >> 3) & 1;
            int j   = u & 7;
            int co  = mt * 32 + i31;
            int ci  = ks * 16 + h * 8 + j;
            Wd[u] = (_Float16)Ws[((size_t)co * 64 + ci) * 9 + pos];
        }
    }
}

// ---------------------------------------------------------------------------
// MFMA implicit-GEMM conv, x-tile 32 (R8 structure, register-budget fixed):
// Xs = 6*34*64 halves = 26.1 KB -> LDS allows 6 blocks/CU; VGPR ~100-120
// under __launch_bounds__(256,2) (256-VGPR cap: no spill, unlike R8's
// (256,4) which collapsed the budget to 64 and spilled) -> 4 blocks/CU =
// 16 waves/CU, 2x the x-64 version's TLP.  Register weight ring depth 4
// (global/L2 weights).  Merged grid (10, 24, 4) = 960 blocks <= 1024
// capacity -> single dispatch wave.
// Phase 1 (all blocks): ext rows rg*4+w -> OutE.
// Phase 2 (rg<16): one top row tr=rg at this x-strip -> OutT (wave 0).
// MODE 1: D[m=x][n=co] -> [b][OH][320][64];  MODE 2: D[m=co][n=x].
// X fragments from the XOR-swizzled Xs tile (stride 34):
//   elem(row, x, c8) at (row*34+x)*64 + (c8 ^ (x&7))*8   (halves)
// ---------------------------------------------------------------------------
template<int MODE>
__global__ __launch_bounds__(256, 2) void conv_kernel(
    const _Float16* __restrict__ Xt, const _Float16* __restrict__ Wfl,
    _Float16* __restrict__ OutE, _Float16* __restrict__ OutT, ShiftInfo si)
{
    __shared__ __align__(16) _Float16 Xs[6 * 34 * 64];   // 26,112 B
    const int xt = blockIdx.x, rg = blockIdx.y, b = blockIdx.z;
    const int x0 = xt * 32;
    const int t  = threadIdx.x;
    const int wv = t >> 6, l = t & 63;
    const int i31 = l & 31, h = l >> 5;

    int grow[6];
#pragma unroll
    for (int r = 0; r < 6; ++r) grow[r] = rg * 4 + r;   // rg==23: rows 96,97 OOB

    // interior: 24 chunks (6 rows x 4 chunks of 8 x-groups), 6 per wave.
    // Pre-swizzled global source: lane l loads logical c8=(l&7)^(x&7) so the
    // LINEAR LDS write lands data where the swizzled reader expects it.
    {
#pragma unroll
        for (int j = 0; j < 6; ++j) {
            int k = wv + 4 * j;          // 0..23
            int r = k >> 2, c = k & 3;
            if ((unsigned)grow[r] < HH) {
                int x  = 1 + 8 * c + (l >> 3);       // 1..32 (always in-image)
                int c8 = (l & 7) ^ (x & 7);
                const _Float16* g =
                    &Xt[((size_t)(b * HH + grow[r]) * WW + (x0 - 1 + x)) * 64 + c8 * 8];
                gl_lds16(g, &Xs[(r * 34 + 1 + 8 * c) * 64]);
            }
        }
    }

    // zero-fill rows that are out of image (only rg==23: rows 4,5)
#pragma unroll
    for (int r = 0; r < 6; ++r) {
        if ((unsigned)grow[r] >= HH) {
            for (int u = t; u < 34 * 8; u += 256) {
                float4 zz = make_float4(0.f, 0.f, 0.f, 0.f);
                *(float4*)&Xs[r * (34 * 64) + u * 8] = zz;
            }
        }
    }

    // halo x=0 and x=33 (bounds-checked scalar path, 96 threads)
    if (t < 96) {
        int r  = t >> 4, hx = (t >> 3) & 1, c8 = t & 7;
        int x  = hx ? 33 : 0;
        int gx = x0 - 1 + x;
        float4 v = make_float4(0.f, 0.f, 0.f, 0.f);
        if ((unsigned)grow[r] < HH && (unsigned)gx < WW)
            v = *(const float4*)&Xt[((size_t)(b * HH + grow[r]) * WW + gx) * 64 + c8 * 8];
        *(float4*)&Xs[(r * 34 + x) * 64 + ((c8 ^ (x & 7)) * 8)] = v;
    }
    __syncthreads();

    floatx16 acc[2];
#pragma unroll
    for (int c = 0; c < 2; ++c)
        acc[c] = (floatx16){0.f,0.f,0.f,0.f, 0.f,0.f,0.f,0.f,
                            0.f,0.f,0.f,0.f, 0.f,0.f,0.f,0.f};

    // register weight ring, depth 4 (R8-verified body)
    {
        int xsw[3], xbase[3];
#pragma unroll
        for (int kx = 0; kx < 3; ++kx) {
            int x = i31 + kx;
            xsw[kx]   = x & 7;
            xbase[kx] = x * 64;
        }
        const int rowb = wv * (34 * 64);
        const _Float16* wp0 = Wfl + i31 * 16 + h * 8;
        half8_t fw0[4], fw1[4], fx0[4];

        auto ld = [&](int idx, int s) {
            const int pos = idx >> 2, ks = idx & 3;
            const int ky = pos / 3, kx = pos - ky * 3;
            const _Float16* wp = wp0 + pos * 4096 + ks * 512;
            fw0[s] = *(const half8_t*)(wp);
            fw1[s] = *(const half8_t*)(wp + 2048);
            const int c8  = ks * 2 + h;
            const int off = rowb + ky * (34 * 64) + xbase[kx] + ((c8 ^ xsw[kx]) * 8);
            fx0[s] = *(const half8_t*)(Xs + off);
        };

#pragma unroll
        for (int s = 0; s < 3; ++s) ld(s, s);

#pragma unroll
        for (int i = 0; i < 36; ++i) {
            if (i + 3 < 36) ld(i + 3, (i + 3) & 3);
            const int s = i & 3;
            if (MODE == 1) {
                acc[0] = __builtin_amdgcn_mfma_f32_32x32x16_f16(fx0[s], fw0[s], acc[0], 0, 0, 0);
                acc[1] = __builtin_amdgcn_mfma_f32_32x32x16_f16(fx0[s], fw1[s], acc[1], 0, 0, 0);
            } else {
                acc[0] = __builtin_amdgcn_mfma_f32_32x32x16_f16(fw0[s], fx0[s], acc[0], 0, 0, 0);
                acc[1] = __builtin_amdgcn_mfma_f32_32x32x16_f16(fw1[s], fx0[s], acc[1], 0, 0, 0);
            }
        }
    }

    // phase-1 epilogue: ext rows -> OutE
    {
        const int om = rg * 4 + wv;
#pragma unroll
        for (int c = 0; c < 2; ++c)
#pragma unroll
            for (int r = 0; r < 16; ++r) {
                int dm = (r & 3) + 8 * (r >> 2) + 4 * h;
                if (MODE == 1) {
                    int x  = x0 + dm;
                    int co = c * 32 + i31;
                    OutE[((size_t)(b * HH + om) * WW + x) * 64 + co] = (_Float16)acc[c][r];
                } else {
                    int co = c * 32 + dm;
                    int x  = x0 + i31;
                    OutE[((size_t)(b * 64 + co) * HH + om) * WW + x] = (_Float16)acc[c][r];
                }
            }
    }

    // ---------------- phase 2: one top row for rg<16 ----------------
    if (rg < 16) {
        const int tr = rg;
        const int trow = si.rows[tr];            // always in [0,95]
        __syncthreads();                         // all waves done reading Xs

        // wave 0 preloads the 24 weight fragments for pos 0..2 (L2-resident)
        half8_t fwp0[12], fwp1[12];
        if (wv == 0) {
#pragma unroll
            for (int p = 0; p < 3; ++p)
#pragma unroll
                for (int ks = 0; ks < 4; ++ks) {
                    const _Float16* wp = Wfl + p * 4096 + ks * 512 + i31 * 16 + h * 8;
                    fwp0[p * 4 + ks] = *(const half8_t*)(wp);
                    fwp1[p * 4 + ks] = *(const half8_t*)(wp + 2048);
                }
        }

        // stage row trow into Xs row 0: interior 4 chunks (1 per wave)
        {
            int c = wv;                          // 0..3
            int x = 1 + 8 * c + (l >> 3);        // 1..32, always in-image
            int c8 = (l & 7) ^ (x & 7);
            gl_lds16(&Xt[((size_t)(b * HH + trow) * WW + (x0 - 1 + x)) * 64 + c8 * 8],
                     &Xs[(1 + 8 * c) * 64]);
        }
        // halo x=0 / x=33
        if (t < 16) {
            int hx = t >> 3, c8 = t & 7;
            int x  = hx ? 33 : 0;
            int gx = x0 - 1 + x;
            float4 v = make_float4(0.f, 0.f, 0.f, 0.f);
            if ((unsigned)gx < WW)
                v = *(const float4*)&Xt[((size_t)(b * HH + trow) * WW + gx) * 64 + c8 * 8];
            *(float4*)&Xs[x * 64 + ((c8 ^ (x & 7)) * 8)] = v;
        }
        __syncthreads();                         // staging drained

        if (wv == 0) {
            floatx16 a2[2];
#pragma unroll
            for (int c = 0; c < 2; ++c)
                a2[c] = (floatx16){0.f,0.f,0.f,0.f, 0.f,0.f,0.f,0.f,
                                   0.f,0.f,0.f,0.f, 0.f,0.f,0.f,0.f};
#pragma unroll
            for (int p = 0; p < 3; ++p) {
                const int x = i31 + p;           // 0..33
#pragma unroll
                for (int ks = 0; ks < 4; ++ks) {
                    const int c8  = ks * 2 + h;
                    const int off = x * 64 + ((c8 ^ (x & 7)) * 8);
                    half8_t fx0v = *(const half8_t*)(Xs + off);
                    half8_t w0 = fwp0[p * 4 + ks], w1 = fwp1[p * 4 + ks];
                    if (MODE == 1) {
                        a2[0] = __builtin_amdgcn_mfma_f32_32x32x16_f16(fx0v, w0, a2[0], 0, 0, 0);
                        a2[1] = __builtin_amdgcn_mfma_f32_32x32x16_f16(fx0v, w1, a2[1], 0, 0, 0);
                    } else {
                        a2[0] = __builtin_amdgcn_mfma_f32_32x32x16_f16(w0, fx0v, a2[0], 0, 0, 0);
                        a2[1] = __builtin_amdgcn_mfma_f32_32x32x16_f16(w1, fx0v, a2[1], 0, 0, 0);
                    }
                }
            }
#pragma unroll
            for (int c = 0; c < 2; ++c)
#pragma unroll
                for (int r = 0; r < 16; ++r) {
                    int dm = (r & 3) + 8 * (r >> 2) + 4 * h;
                    if (MODE == 1) {
                        int x  = x0 + dm;
                        int co = c * 32 + i31;
                        OutT[((size_t)(b * 16 + tr) * WW + x) * 64 + co] = (_Float16)a2[c][r];
                    } else {
                        int co = c * 32 + dm;
                        int x  = x0 + i31;
                        OutT[((size_t)(b * 64 + co) * 16 + tr) * WW + x] = (_Float16)a2[c][r];
                    }
                }
        }
    }
}

// ---------------------------------------------------------------------------
// blend1: C[b][96][320][64] + T[b][16][320][64] -> Xt2[b][96][320][64] (f16)
// x-tile = 1 column: grid (320 xt, 4 b), block 256 = 8 co8 x 32 yt.
// LDS layout bank-swizzled via CSW (conflict-free reads).
// ---------------------------------------------------------------------------
__global__ __launch_bounds__(256) void blend1_kernel(
    const _Float16* __restrict__ Cb, const _Float16* __restrict__ T,
    const float* __restrict__ bias, _Float16* __restrict__ Xt2, ShiftInfo si)
{
    __shared__ __align__(16) _Float16 Cs[96 * 64];   // [row][co] 12.3 KB
    __shared__ __align__(16) _Float16 Ts[16 * 64];   // 2 KB
    const int x0 = blockIdx.x, b = blockIdx.y, t = threadIdx.x;
    const half8_t z = {0,0,0,0,0,0,0,0};

    {
        const int w = t >> 6, l = t & 63;
        const int c8s = (l & 7) ^ ((l >> 3) & 7);    // = (l&7) ^ (row&7)
#pragma unroll
        for (int j = 0; j < 3; ++j) {
            int k = w + 4 * j;                   // 0..11, 8 rows each
            int row = 8 * k + (l >> 3);
            gl_lds16(&Cb[((size_t)(b * HH + row) * WW + x0) * 64 + c8s * 8],
                     &Cs[k * 512]);
        }
        if (w < 2) {
            int row = 8 * w + (l >> 3);
            gl_lds16(&T[((size_t)(b * 16 + row) * WW + x0) * 64 + c8s * 8],
                     &Ts[w * 512]);
        }
    }
    __syncthreads();

    const int co8 = t & 7, yt = t >> 3;
    half8_t bv;
#pragma unroll
    for (int j = 0; j < 8; ++j) bv[j] = (_Float16)bias[co8 * 8 + j];

    const int y0 = yt * 3;
    half8_t cur[NP];
#pragma unroll
    for (int d = 0; d < NP; ++d) {
        int r = y0 + si.s0[d] - 1;
        cur[d] = (r < HH) ? *(const half8_t*)&Cs[CSW(r, co8)] : z;
    }
    for (int y = y0; y < y0 + 3; ++y) {
        half8_t m = z;
#pragma unroll
        for (int d = 0; d < NP; ++d) {
            int r1 = y + si.s0[d];
            half8_t v1 = (r1 < HH) ? *(const half8_t*)&Cs[CSW(r1, co8)] : z;
            half8_t v0 = cur[d];
            cur[d] = v1;
            _Float16 a = (_Float16)si.wa[d], wg = (_Float16)si.wb[d];
            half8_t p;
            if (y == 0) {
                half8_t t0 = *(const half8_t*)&Ts[CSW(2 * d, co8)];
                half8_t t1 = *(const half8_t*)&Ts[CSW(2 * d + 1, co8)];
                p = a * (v0 - t0) + wg * (v1 - t1);
            } else {
                p = a * v0 + wg * v1;
            }
            m = (d == 0) ? p : __builtin_elementwise_max(m, p);
        }
        half8_t o = __builtin_elementwise_max(m + bv, z);
        *(half8_t*)&Xt2[((size_t)(b * HH + y) * WW + x0) * 64 + co8 * 8] = o;
    }
}

// ---------------------------------------------------------------------------
// blend2: C[b][64][96][320] + T[b][64][16][320] -> Out fp32 [b][64][96][320]
// grid 1280 = (xt 5) x (co 64) x (b 4), block 256.
// LDS layout bank-swizzled via CSW (conflict-free reads).
// ---------------------------------------------------------------------------
__global__ __launch_bounds__(256) void blend2_kernel(
    const _Float16* __restrict__ Cb, const _Float16* __restrict__ T,
    const float* __restrict__ bias, float* __restrict__ Out, ShiftInfo si)
{
    __shared__ __align__(16) _Float16 Cs[96 * 64];
    __shared__ __align__(16) _Float16 Ts[16 * 64];
    const int task = blockIdx.x, t = threadIdx.x;
    const int xt = task % 5;
    const int rem = task / 5;
    const int co = rem & 63;
    const int b  = rem >> 6;
    const int x0 = xt * 64;
    const half8_t z = {0,0,0,0,0,0,0,0};

    {
        const int w = t >> 6, l = t & 63;
        const int x8s = (l & 7) ^ ((l >> 3) & 7);    // = (l&7) ^ (row&7)
#pragma unroll
        for (int j = 0; j < 3; ++j) {
            int k = w + 4 * j;                   // 0..11, 8 rows each
            int row = 8 * k + (l >> 3);
            gl_lds16(&Cb[((size_t)(b * 64 + co) * HH + row) * WW + x0 + x8s * 8],
                     &Cs[k * 512]);
        }
        if (w < 2) {
            int row = 8 * w + (l >> 3);
            gl_lds16(&T[((size_t)(b * 64 + co) * 16 + row) * WW + x0 + x8s * 8],
                     &Ts[w * 512]);
        }
    }
    __syncthreads();

    const int x8 = t & 7, yt = t >> 3;
    const float bvf = bias[co];
    const int y0 = yt * 3;

    half8_t cur[NP];
#pragma unroll
    for (int d = 0; d < NP; ++d) {
        int r = y0 + si.s0[d] - 1;
        cur[d] = (r < HH) ? *(const half8_t*)&Cs[CSW(r, x8)] : z;
    }
    for (int y = y0; y < y0 + 3; ++y) {
        half8_t m = z;
#pragma unroll
        for (int d = 0; d < NP; ++d) {
            int r1 = y + si.s0[d];
            half8_t v1 = (r1 < HH) ? *(const half8_t*)&Cs[CSW(r1, x8)] : z;
            half8_t v0 = cur[d];
            cur[d] = v1;
            _Float16 a = (_Float16)si.wa[d], wg = (_Float16)si.wb[d];
            half8_t p;
            if (y == 0) {
                half8_t t0 = *(const half8_t*)&Ts[CSW(2 * d, x8)];
                half8_t t1 = *(const half8_t*)&Ts[CSW(2 * d + 1, x8)];
                p = a * (v0 - t0) + wg * (v1 - t1);
            } else {
                p = a * v0 + wg * v1;
            }
            m = (d == 0) ? p : __builtin_elementwise_max(m, p);
        }
        float4 o0, o1;
        o0.x = fmaxf((float)m[0] + bvf, 0.f);
        o0.y = fmaxf((float)m[1] + bvf, 0.f);
        o0.z = fmaxf((float)m[2] + bvf, 0.f);
        o0.w = fmaxf((float)m[3] + bvf, 0.f);
        o1.x = fmaxf((float)m[4] + bvf, 0.f);
        o1.y = fmaxf((float)m[5] + bvf, 0.f);
        o1.z = fmaxf((float)m[6] + bvf, 0.f);
        o1.w = fmaxf((float)m[7] + bvf, 0.f);
        float* op = Out + ((size_t)(b * 64 + co) * HH + y) * WW + x0 + x8 * 8;
        *(float4*)op = o0;
        *(float4*)(op + 4) = o1;
    }
}

// ---------------------------------------------------------------------------
extern "C" void kernel_launch(void* const* d_in, const int* in_sizes, int n_in,
                              void* d_out, int out_size, void* d_ws, size_t ws_size,
                              hipStream_t stream) {
    const float* x  = (const float*)d_in[0];
    const float* W1 = (const float*)d_in[1];
    const float* b1 = (const float*)d_in[2];
    const float* W2 = (const float*)d_in[3];
    const float* b2 = (const float*)d_in[4];
    float* out = (float*)d_out;

    _Float16* Xt1 = (_Float16*)d_ws;            // 7,864,320 halves
    _Float16* Cb  = Xt1 + 7864320;              // 7,864,320
    _Float16* T   = Cb  + 7864320;              // 1,310,720
    _Float16* Wf  = T   + 1310720;              // 73,728 (both layers, MFMA layout)
    _Float16* Xt2 = (_Float16*)d_out;           // f16 scratch inside d_out

    ShiftInfo si;
    for (int d = 0; d < NP; ++d) {
        double disp = 0.02 + d * (0.98 / 7.0);
        double sh   = 76.0 * disp;
        int s0      = (int)floor(sh);
        double w    = sh - (double)s0;
        si.s0[d] = s0;
        si.wa[d] = (float)(1.0 - w);
        si.wb[d] = (float)w;
        si.rows[2 * d]     = s0 - 1;
        si.rows[2 * d + 1] = s0;
    }

    prep_kernel<<<dim3(786), 256, 0, stream>>>(x, W1, W2, Xt1, Wf);

    conv_kernel<1><<<dim3(10, 24, 4), 256, 0, stream>>>(Xt1, Wf, Cb, T, si);
    blend1_kernel<<<dim3(320, 4), 256, 0, stream>>>(Cb, T, b1, Xt2, si);

    conv_kernel<2><<<dim3(10, 24, 4), 256, 0, stream>>>(Xt2, Wf + 36864, Cb, T, si);
    blend2_kernel<<<dim3(1280), 256, 0, stream>>>(Cb, T, b2, out, si);
}